// Round 6
// baseline (381.811 us; speedup 1.0000x reference)
//
#include <hip/hip_runtime.h>
#include <hip/hip_bf16.h>
#include <math.h>

#define B_ 2
#define S_ 2048
#define E_ 1024
#define H_ 16
#define D_ 64
#define M_ (B_*S_)

typedef __attribute__((ext_vector_type(8))) short short8v;
typedef __attribute__((ext_vector_type(4))) float floatx4;

__device__ __forceinline__ short f2bf(float f) {
    union { float f; unsigned u; } x; x.f = f;
    unsigned r = (x.u + 0x7fffu + ((x.u >> 16) & 1u)) >> 16;  // RNE
    return (short)r;
}

// pack two fp32 -> two bf16 in one v_perm_b32 (round-half-up)
__device__ __forceinline__ unsigned pk_bf16(float a, float b) {
    union { float f; unsigned u; } x, y;
    x.f = a; y.f = b;
    return __builtin_amdgcn_perm(y.u + 0x8000u, x.u + 0x8000u, 0x07060302u);
}

__device__ __forceinline__ float fast_exp2(float x) {
#if __has_builtin(__builtin_amdgcn_exp2f)
    return __builtin_amdgcn_exp2f(x);
#else
    return __expf(x * 0.6931471805599453f);
#endif
}

// async global->LDS, 16B per lane; LDS dest = wave-uniform base + lane*16
__device__ __forceinline__ void gl2lds16(const void* g, void* l) {
    __builtin_amdgcn_global_load_lds(
        (const __attribute__((address_space(1))) void*)g,
        (__attribute__((address_space(3))) void*)l, 16, 0, 0);
}

// ---------------------------------------------------------------------------
// Pre-pass 1: x fp32 -> bf16 flat copy.
// ---------------------------------------------------------------------------
__global__ __launch_bounds__(256) void convert_x(
    const float* __restrict__ x, short* __restrict__ xb)
{
    const size_t i = ((size_t)blockIdx.x*256 + threadIdx.x) * 8;
    float4 a = *(const float4*)(x + i);
    float4 b = *(const float4*)(x + i + 4);
    int4 p = { (int)pk_bf16(a.x,a.y), (int)pk_bf16(a.z,a.w),
               (int)pk_bf16(b.x,b.y), (int)pk_bf16(b.z,b.w) };
    *(int4*)(xb + i) = p;
}

// ---------------------------------------------------------------------------
// Pre-pass 2: W [k][n] fp32 -> Wt [n][k] bf16 (32x32 LDS tile transpose).
// ---------------------------------------------------------------------------
__global__ __launch_bounds__(256) void transpose_w(
    const float* __restrict__ W0, const float* __restrict__ W1,
    const float* __restrict__ W2, const float* __restrict__ W3,
    short* __restrict__ T0, short* __restrict__ T1,
    short* __restrict__ T2, short* __restrict__ T3)
{
    const int z = blockIdx.z;
    const float* W = (z==0)?W0:(z==1)?W1:(z==2)?W2:W3;
    short*       T = (z==0)?T0:(z==1)?T1:(z==2)?T2:T3;
    __shared__ float tile[32][33];
    const int k0 = blockIdx.y*32, n0 = blockIdx.x*32;
    const int r = threadIdx.x >> 5, c = threadIdx.x & 31;
    #pragma unroll
    for (int i=0;i<4;i++)
        tile[r+8*i][c] = W[(size_t)(k0+r+8*i)*E_ + n0 + c];
    __syncthreads();
    #pragma unroll
    for (int i=0;i<4;i++)
        T[(size_t)(n0+r+8*i)*E_ + k0 + c] = f2bf(tile[c][r+8*i]);
}

// ---------------------------------------------------------------------------
// QKV GEMM, m97 structure: 128x128 tile, BK=32, global_load_lds staging.
// ---------------------------------------------------------------------------
__global__ __launch_bounds__(256) void qkv_gemm(
    const short* __restrict__ xb,
    const short* __restrict__ Wtq, const short* __restrict__ Wtk, const short* __restrict__ Wtv,
    const float* __restrict__ bq, const float* __restrict__ bk, const float* __restrict__ bv,
    short* __restrict__ Qo, short* __restrict__ Ko, short* __restrict__ Vo)
{
    const int z = blockIdx.z;
    const short* Wt = (z==0) ? Wtq : (z==1) ? Wtk : Wtv;
    const float* bb = (z==0) ? bq  : (z==1) ? bk  : bv;
    short* out      = (z==0) ? Qo  : (z==1) ? Ko  : Vo;
    const float sc  = (z==0) ? 0.18033688011112042f : 1.0f;

    __shared__ __align__(16) short As[128*32];
    __shared__ __align__(16) short Bs[128*32];

    const int t = threadIdx.x;
    const int wave = t >> 6, lane = t & 63;
    const int quad = lane >> 4, l15 = lane & 15;
    const int m0 = blockIdx.y*128, n0 = blockIdx.x*128;
    const int mq = (wave & 1)*64, nq = (wave >> 1)*64;
    const int srow = lane >> 2, scol = (lane & 3)*8;

    floatx4 acc[4][4];
    #pragma unroll
    for (int i=0;i<4;i++)
        #pragma unroll
        for (int j=0;j<4;j++) acc[i][j] = (floatx4){0.f,0.f,0.f,0.f};

    for (int k0 = 0; k0 < E_; k0 += 32) {
        #pragma unroll
        for (int p=0;p<2;p++) {
            const int rb = 16*(wave*2 + p);
            gl2lds16(xb + (size_t)(m0+rb+srow)*E_ + k0 + scol, &As[rb*32]);
            gl2lds16(Wt + (size_t)(n0+rb+srow)*E_ + k0 + scol, &Bs[rb*32]);
        }
        __syncthreads();
        short8v a[4], b[4];
        #pragma unroll
        for (int mt=0;mt<4;mt++) a[mt] = *(const short8v*)&As[(mq+mt*16+l15)*32 + quad*8];
        #pragma unroll
        for (int nt=0;nt<4;nt++) b[nt] = *(const short8v*)&Bs[(nq+nt*16+l15)*32 + quad*8];
        #pragma unroll
        for (int mt=0;mt<4;mt++)
            #pragma unroll
            for (int nt=0;nt<4;nt++)
                acc[mt][nt] = __builtin_amdgcn_mfma_f32_16x16x32_bf16(a[mt], b[nt], acc[mt][nt], 0,0,0);
        __syncthreads();
    }

    #pragma unroll
    for (int nt=0;nt<4;nt++) {
        const int n = n0 + nq + nt*16 + l15;
        const float bias = bb[n];
        const int h = n >> 6, d = n & 63;
        #pragma unroll
        for (int mt=0;mt<4;mt++) {
            #pragma unroll
            for (int r=0;r<4;r++) {
                const int m = m0 + mq + mt*16 + quad*4 + r;
                const int b2 = m >> 11, s = m & (S_-1);
                const float v = (acc[mt][nt][r] + bias) * sc;
                if (z == 2) out[((size_t)((b2<<4)+h)*D_ + d)*S_ + s] = f2bf(v);
                else        out[((size_t)((b2<<4)+h)*S_ + s)*D_ + d] = f2bf(v);
            }
        }
    }
}

// ---------------------------------------------------------------------------
// Causal flash attention, software-pipelined K-loop:
//   iter t:  qk(t) -> prefetch k(t+1) -> pv(t-1) -> soft(t) -> prefetch v(t+1)
// P ping-pong in per-wave LDS (no barriers, no lgkmcnt drains on the path).
// 2 q-tiles per wave (qb+16w, qb+64+16w), 64-key tiles, no-max exp2 softmax.
// Q bf16 [B,H,S,D] (exp2-scaled); K [B,H,S,D]; V [B,H,D,S]. Out bf16 [B,S,H,D].
// __launch_bounds__(256,1): min 1 wave/EU -> allocator may use up to 512
// VGPRs. R5 lesson: bare (256) targeted default occupancy, capped VGPR at
// 112, and spilled the K/V double buffers to scratch (554 MB WRITE_SIZE,
// 3.3 TB/s of spill traffic). Grid is 2 blocks/CU anyway, so high VGPR is free.
// ---------------------------------------------------------------------------
__global__ __launch_bounds__(256, 1) void attn_kernel(
    const short* __restrict__ Q, const short* __restrict__ K, const short* __restrict__ V,
    short* __restrict__ AO)
{
    const int bh = blockIdx.x;
    const int qb = (gridDim.y - 1 - blockIdx.y) * 128;
    const int t = threadIdx.x;
    const int wave = t >> 6, lane = t & 63;
    const int quad = lane >> 4, l15 = lane & 15;

    const short* Qp = Q + (size_t)bh * (S_*D_);
    const short* Kp = K + (size_t)bh * (S_*D_);
    const short* Vp = V + (size_t)bh * (S_*D_);

    // per wave: [parity][qtile A/B] x (16 x 72)
    __shared__ __align__(16) short Psl[4*4*16*72];
    short* pwav = Psl + wave*(4*16*72);
    #define PBUF(par, ab) (pwav + ((par)*2 + (ab))*(16*72))

    const int qA = qb + wave*16;
    const int qB = qb + 64 + wave*16;
    const short* qa = Qp + (size_t)(qA + l15)*D_ + quad*8;
    const short8v qA0 = *(const short8v*)qa, qA1 = *(const short8v*)(qa + 32);
    const short* qbp = Qp + (size_t)(qB + l15)*D_ + quad*8;
    const short8v qB0 = *(const short8v*)qbp, qB1 = *(const short8v*)(qbp + 32);

    floatx4 oA[4], oB[4];
    #pragma unroll
    for (int i=0;i<4;i++) { oA[i] = (floatx4){0,0,0,0}; oB[i] = (floatx4){0,0,0,0}; }
    float tsA[4] = {0,0,0,0}, tsB[4] = {0,0,0,0};

    const int full = qb >> 6;        // tile index of A's diagonal
    const int ntiles = full + 2;     // last tile (full+1) is B's diagonal

    auto load_k = [&](short8v (&kb)[4][2], int kt) {
        const int k0 = kt << 6;
        #pragma unroll
        for (int h=0; h<4; h++) {
            const short* kr = Kp + (size_t)(k0 + 4*l15 + h)*D_ + quad*8;
            kb[h][0] = *(const short8v*)kr;
            kb[h][1] = *(const short8v*)(kr + 32);
        }
    };
    auto load_v = [&](short8v (&vb)[4][2], int kt) {
        const int k0 = kt << 6;
        #pragma unroll
        for (int dt=0; dt<4; dt++) {
            const short* vr = Vp + (size_t)(dt*16 + l15)*S_ + k0 + quad*8;
            vb[dt][0] = *(const short8v*)vr;
            vb[dt][1] = *(const short8v*)(vr + 32);
        }
    };
    auto qk = [&](short8v (&kb)[4][2], const short8v& q0f, const short8v& q1f,
                  floatx4 (&s)[4]) {
        #pragma unroll
        for (int h=0; h<4; h++) {
            s[h] = (floatx4){0.f,0.f,0.f,0.f};
            s[h] = __builtin_amdgcn_mfma_f32_16x16x32_bf16(q0f, kb[h][0], s[h], 0,0,0);
            s[h] = __builtin_amdgcn_mfma_f32_16x16x32_bf16(q1f, kb[h][1], s[h], 0,0,0);
        }
    };
    auto soft = [&](floatx4 (&s)[4], float* ts, short* pw) {
        #pragma unroll
        for (int r=0; r<4; r++) {
            float p0 = fast_exp2(s[0][r]), p1 = fast_exp2(s[1][r]);
            float p2 = fast_exp2(s[2][r]), p3 = fast_exp2(s[3][r]);
            ts[r] += (p0 + p1) + (p2 + p3);
            int2 pkv = { (int)pk_bf16(p0, p1), (int)pk_bf16(p2, p3) };
            *(int2*)(pw + (quad*4 + r)*72 + l15*4) = pkv;
        }
    };
    auto soft_mask = [&](floatx4 (&s)[4], float* ts, short* pw) {
        #pragma unroll
        for (int r=0; r<4; r++) {
            const int rr = wave*16 + quad*4 + r;
            float p[4];
            #pragma unroll
            for (int h=0; h<4; h++)
                p[h] = (4*l15 + h > rr) ? 0.f : fast_exp2(s[h][r]);
            ts[r] += (p[0] + p[1]) + (p[2] + p[3]);
            int2 pkv = { (int)pk_bf16(p[0], p[1]), (int)pk_bf16(p[2], p[3]) };
            *(int2*)(pw + (quad*4 + r)*72 + l15*4) = pkv;
        }
    };
    auto pv = [&](short8v (&vb)[4][2], short* pw, floatx4 (&o)[4]) {
        const short8v pf0 = *(const short8v*)(pw + l15*72 + quad*8);
        const short8v pf1 = *(const short8v*)(pw + l15*72 + 32 + quad*8);
        #pragma unroll
        for (int dt=0; dt<4; dt++) {
            o[dt] = __builtin_amdgcn_mfma_f32_16x16x32_bf16(pf0, vb[dt][0], o[dt], 0,0,0);
            o[dt] = __builtin_amdgcn_mfma_f32_16x16x32_bf16(pf1, vb[dt][1], o[dt], 0,0,0);
        }
    };

    short8v kb[2][4][2], vb[2][4][2];

    // ---- prologue: tile 0 ----
    load_k(kb[0], 0);
    load_v(vb[0], 0);
    {
        floatx4 sA[4], sB[4];
        qk(kb[0], qA0, qA1, sA);
        qk(kb[0], qB0, qB1, sB);
        load_k(kb[1], 1);
        if (full == 0) soft_mask(sA, tsA, PBUF(0,0));
        else           soft     (sA, tsA, PBUF(0,0));
        soft(sB, tsB, PBUF(0,1));
        load_v(vb[1], 1);
    }

    // ---- pipelined main loop: tiles 1 .. ntiles-1 ----
    for (int kt = 1; kt < ntiles; kt++) {
        const int cur = kt & 1, prv = cur ^ 1;
        const bool skipA = (kt == full + 1);
        floatx4 sA[4], sB[4];
        if (!skipA) qk(kb[cur], qA0, qA1, sA);
        qk(kb[cur], qB0, qB1, sB);
        if (kt + 1 < ntiles) load_k(kb[prv], kt + 1);

        // PV for tile kt-1 (P written last iteration; V loaded 2 iters ago)
        pv(vb[prv], PBUF(prv,0), oA);
        pv(vb[prv], PBUF(prv,1), oB);

        if (!skipA) {
            if (kt == full) soft_mask(sA, tsA, PBUF(cur,0));
            else            soft     (sA, tsA, PBUF(cur,0));
        }
        if (skipA) soft_mask(sB, tsB, PBUF(cur,1));
        else       soft     (sB, tsB, PBUF(cur,1));

        if (kt + 1 < ntiles) load_v(vb[prv], kt + 1);
    }

    // ---- epilogue: PV for the last tile (B only; A fully masked there) ----
    {
        const int lt = (ntiles - 1) & 1;
        pv(vb[lt], PBUF(lt,1), oB);
    }

    float lA[4], lB[4];
    #pragma unroll
    for (int r=0; r<4; r++) {
        float a = tsA[r], b = tsB[r];
        #pragma unroll
        for (int off=1; off<16; off<<=1) {
            a += __shfl_xor(a, off);
            b += __shfl_xor(b, off);
        }
        lA[r] = a; lB[r] = b;
    }

    const int b = bh >> 4, h = bh & 15;
    #pragma unroll
    for (int dt=0; dt<4; dt++) {
        #pragma unroll
        for (int r=0; r<4; r++) {
            const int d = dt*16 + l15;
            const int sA_ = qA + quad*4 + r;
            const int sB_ = qB + quad*4 + r;
            AO[((size_t)(b*S_ + sA_)*H_ + h)*D_ + d] = f2bf(oA[dt][r] / lA[r]);
            AO[((size_t)(b*S_ + sB_)*H_ + h)*D_ + d] = f2bf(oB[dt][r] / lB[r]);
        }
    }
    #undef PBUF
}

// ---------------------------------------------------------------------------
// Output GEMM, m97 structure. A = AO bf16 [4096,1024]; B = Wto bf16 [n][k].
// ---------------------------------------------------------------------------
__global__ __launch_bounds__(256) void out_gemm(
    const short* __restrict__ A, const short* __restrict__ Wto,
    const float* __restrict__ bo, float* __restrict__ out)
{
    __shared__ __align__(16) short As[128*32];
    __shared__ __align__(16) short Bs[128*32];

    const int t = threadIdx.x;
    const int wave = t >> 6, lane = t & 63;
    const int quad = lane >> 4, l15 = lane & 15;
    const int m0 = blockIdx.y*128, n0 = blockIdx.x*128;
    const int mq = (wave & 1)*64, nq = (wave >> 1)*64;
    const int srow = lane >> 2, scol = (lane & 3)*8;

    floatx4 acc[4][4];
    #pragma unroll
    for (int i=0;i<4;i++)
        #pragma unroll
        for (int j=0;j<4;j++) acc[i][j] = (floatx4){0.f,0.f,0.f,0.f};

    for (int k0 = 0; k0 < E_; k0 += 32) {
        #pragma unroll
        for (int p=0;p<2;p++) {
            const int rb = 16*(wave*2 + p);
            gl2lds16(A   + (size_t)(m0+rb+srow)*E_ + k0 + scol, &As[rb*32]);
            gl2lds16(Wto + (size_t)(n0+rb+srow)*E_ + k0 + scol, &Bs[rb*32]);
        }
        __syncthreads();
        short8v a[4], b[4];
        #pragma unroll
        for (int mt=0;mt<4;mt++) a[mt] = *(const short8v*)&As[(mq+mt*16+l15)*32 + quad*8];
        #pragma unroll
        for (int nt=0;nt<4;nt++) b[nt] = *(const short8v*)&Bs[(nq+nt*16+l15)*32 + quad*8];
        #pragma unroll
        for (int mt=0;mt<4;mt++)
            #pragma unroll
            for (int nt=0;nt<4;nt++)
                acc[mt][nt] = __builtin_amdgcn_mfma_f32_16x16x32_bf16(a[mt], b[nt], acc[mt][nt], 0,0,0);
        __syncthreads();
    }

    #pragma unroll
    for (int nt=0;nt<4;nt++) {
        const int n = n0 + nq + nt*16 + l15;
        const float bias = bo[n];
        #pragma unroll
        for (int mt=0;mt<4;mt++) {
            #pragma unroll
            for (int r=0;r<4;r++) {
                const int m = m0 + mq + mt*16 + quad*4 + r;
                out[(size_t)m*E_ + n] = acc[mt][nt][r] + bias;
            }
        }
    }
}

extern "C" void kernel_launch(void* const* d_in, const int* in_sizes, int n_in,
                              void* d_out, int out_size, void* d_ws, size_t ws_size,
                              hipStream_t stream)
{
    const float* x  = (const float*)d_in[0];
    const float* Wq = (const float*)d_in[1];
    const float* bq = (const float*)d_in[2];
    const float* Wk = (const float*)d_in[3];
    const float* bk = (const float*)d_in[4];
    const float* Wv = (const float*)d_in[5];
    const float* bv = (const float*)d_in[6];
    const float* Wo = (const float*)d_in[7];
    const float* bo = (const float*)d_in[8];

    short* xb  = (short*)d_ws;                   // bf16 [4096,1024]
    short* Tq  = xb  + (size_t)M_ * E_;          // bf16 Wq^T [n][k]
    short* Tk  = Tq  + (size_t)E_ * E_;
    short* Tv  = Tk  + (size_t)E_ * E_;
    short* To  = Tv  + (size_t)E_ * E_;
    short* Qw  = To  + (size_t)E_ * E_;          // bf16 [B,H,S,D] (exp2-scaled)
    short* Kw  = Qw  + (size_t)M_ * E_;          // bf16 [B,H,S,D]
    short* Vw  = Kw  + (size_t)M_ * E_;          // bf16 [B,H,D,S]
    short* AOw = Vw  + (size_t)M_ * E_;          // bf16 [B,S,H,D]

    dim3 blk(256);
    convert_x<<<dim3((M_*E_)/(256*8)), blk, 0, stream>>>(x, xb);
    transpose_w<<<dim3(E_/32, E_/32, 4), blk, 0, stream>>>(Wq, Wk, Wv, Wo, Tq, Tk, Tv, To);
    qkv_gemm<<<dim3(E_/128, M_/128, 3), blk, 0, stream>>>(xb, Tq, Tk, Tv, bq, bk, bv, Qw, Kw, Vw);
    attn_kernel<<<dim3(B_*H_, S_/128), blk, 0, stream>>>(Qw, Kw, Vw, AOw);
    out_gemm<<<dim3(E_/128, M_/128), blk, 0, stream>>>(AOw, To, bo, (float*)d_out);
}

// Round 7
// 218.329 us; speedup vs baseline: 1.7488x; 1.7488x over previous
//
#include <hip/hip_runtime.h>
#include <hip/hip_bf16.h>
#include <math.h>

#define B_ 2
#define S_ 2048
#define E_ 1024
#define H_ 16
#define D_ 64
#define M_ (B_*S_)

typedef __attribute__((ext_vector_type(8))) short short8v;
typedef __attribute__((ext_vector_type(4))) float floatx4;

__device__ __forceinline__ short f2bf(float f) {
    union { float f; unsigned u; } x; x.f = f;
    unsigned r = (x.u + 0x7fffu + ((x.u >> 16) & 1u)) >> 16;  // RNE
    return (short)r;
}

// pack two fp32 -> two bf16 in one v_perm_b32 (round-half-up)
__device__ __forceinline__ unsigned pk_bf16(float a, float b) {
    union { float f; unsigned u; } x, y;
    x.f = a; y.f = b;
    return __builtin_amdgcn_perm(y.u + 0x8000u, x.u + 0x8000u, 0x07060302u);
}

__device__ __forceinline__ float fast_exp2(float x) {
#if __has_builtin(__builtin_amdgcn_exp2f)
    return __builtin_amdgcn_exp2f(x);
#else
    return __expf(x * 0.6931471805599453f);
#endif
}

// async global->LDS, 16B per lane; LDS dest = wave-uniform base + lane*16
__device__ __forceinline__ void gl2lds16(const void* g, void* l) {
    __builtin_amdgcn_global_load_lds(
        (const __attribute__((address_space(1))) void*)g,
        (__attribute__((address_space(3))) void*)l, 16, 0, 0);
}

// ---------------------------------------------------------------------------
// Pre-pass 1: x fp32 -> bf16 flat copy.
// ---------------------------------------------------------------------------
__global__ __launch_bounds__(256) void convert_x(
    const float* __restrict__ x, short* __restrict__ xb)
{
    const size_t i = ((size_t)blockIdx.x*256 + threadIdx.x) * 8;
    float4 a = *(const float4*)(x + i);
    float4 b = *(const float4*)(x + i + 4);
    int4 p = { (int)pk_bf16(a.x,a.y), (int)pk_bf16(a.z,a.w),
               (int)pk_bf16(b.x,b.y), (int)pk_bf16(b.z,b.w) };
    *(int4*)(xb + i) = p;
}

// ---------------------------------------------------------------------------
// Pre-pass 2: W [k][n] fp32 -> Wt [n][k] bf16 (32x32 LDS tile transpose).
// ---------------------------------------------------------------------------
__global__ __launch_bounds__(256) void transpose_w(
    const float* __restrict__ W0, const float* __restrict__ W1,
    const float* __restrict__ W2, const float* __restrict__ W3,
    short* __restrict__ T0, short* __restrict__ T1,
    short* __restrict__ T2, short* __restrict__ T3)
{
    const int z = blockIdx.z;
    const float* W = (z==0)?W0:(z==1)?W1:(z==2)?W2:W3;
    short*       T = (z==0)?T0:(z==1)?T1:(z==2)?T2:T3;
    __shared__ float tile[32][33];
    const int k0 = blockIdx.y*32, n0 = blockIdx.x*32;
    const int r = threadIdx.x >> 5, c = threadIdx.x & 31;
    #pragma unroll
    for (int i=0;i<4;i++)
        tile[r+8*i][c] = W[(size_t)(k0+r+8*i)*E_ + n0 + c];
    __syncthreads();
    #pragma unroll
    for (int i=0;i<4;i++)
        T[(size_t)(n0+r+8*i)*E_ + k0 + c] = f2bf(tile[c][r+8*i]);
}

// ---------------------------------------------------------------------------
// QKV GEMM, m97 structure: 128x128 tile, BK=32, global_load_lds staging.
// ---------------------------------------------------------------------------
__global__ __launch_bounds__(256) void qkv_gemm(
    const short* __restrict__ xb,
    const short* __restrict__ Wtq, const short* __restrict__ Wtk, const short* __restrict__ Wtv,
    const float* __restrict__ bq, const float* __restrict__ bk, const float* __restrict__ bv,
    short* __restrict__ Qo, short* __restrict__ Ko, short* __restrict__ Vo)
{
    const int z = blockIdx.z;
    const short* Wt = (z==0) ? Wtq : (z==1) ? Wtk : Wtv;
    const float* bb = (z==0) ? bq  : (z==1) ? bk  : bv;
    short* out      = (z==0) ? Qo  : (z==1) ? Ko  : Vo;
    const float sc  = (z==0) ? 0.18033688011112042f : 1.0f;

    __shared__ __align__(16) short As[128*32];
    __shared__ __align__(16) short Bs[128*32];

    const int t = threadIdx.x;
    const int wave = t >> 6, lane = t & 63;
    const int quad = lane >> 4, l15 = lane & 15;
    const int m0 = blockIdx.y*128, n0 = blockIdx.x*128;
    const int mq = (wave & 1)*64, nq = (wave >> 1)*64;
    const int srow = lane >> 2, scol = (lane & 3)*8;

    floatx4 acc[4][4];
    #pragma unroll
    for (int i=0;i<4;i++)
        #pragma unroll
        for (int j=0;j<4;j++) acc[i][j] = (floatx4){0.f,0.f,0.f,0.f};

    for (int k0 = 0; k0 < E_; k0 += 32) {
        #pragma unroll
        for (int p=0;p<2;p++) {
            const int rb = 16*(wave*2 + p);
            gl2lds16(xb + (size_t)(m0+rb+srow)*E_ + k0 + scol, &As[rb*32]);
            gl2lds16(Wt + (size_t)(n0+rb+srow)*E_ + k0 + scol, &Bs[rb*32]);
        }
        __syncthreads();
        short8v a[4], b[4];
        #pragma unroll
        for (int mt=0;mt<4;mt++) a[mt] = *(const short8v*)&As[(mq+mt*16+l15)*32 + quad*8];
        #pragma unroll
        for (int nt=0;nt<4;nt++) b[nt] = *(const short8v*)&Bs[(nq+nt*16+l15)*32 + quad*8];
        #pragma unroll
        for (int mt=0;mt<4;mt++)
            #pragma unroll
            for (int nt=0;nt<4;nt++)
                acc[mt][nt] = __builtin_amdgcn_mfma_f32_16x16x32_bf16(a[mt], b[nt], acc[mt][nt], 0,0,0);
        __syncthreads();
    }

    #pragma unroll
    for (int nt=0;nt<4;nt++) {
        const int n = n0 + nq + nt*16 + l15;
        const float bias = bb[n];
        const int h = n >> 6, d = n & 63;
        #pragma unroll
        for (int mt=0;mt<4;mt++) {
            #pragma unroll
            for (int r=0;r<4;r++) {
                const int m = m0 + mq + mt*16 + quad*4 + r;
                const int b2 = m >> 11, s = m & (S_-1);
                const float v = (acc[mt][nt][r] + bias) * sc;
                if (z == 2) out[((size_t)((b2<<4)+h)*D_ + d)*S_ + s] = f2bf(v);
                else        out[((size_t)((b2<<4)+h)*S_ + s)*D_ + d] = f2bf(v);
            }
        }
    }
}

// ---------------------------------------------------------------------------
// Causal flash attention, software-pipelined K-loop with STATIC buffers:
//   iter t:  qk(t) -> load_k(t+1) -> pv(t-1) -> soft(t) -> load_v(t+1)
// R6 lesson: runtime-indexed local arrays (kb[cur]) CANNOT live in registers
// -> 554 MB scratch spill. Here the loop is 2x-unrolled so even tiles use
// kX/vX/P0 and odd tiles kY/vY/P1 — all buffer bindings compile-time.
// qb is a multiple of 128 => ntiles = qb/64+2 is even => last tile is odd
// parity => drain is statically pv(vY,P1).
// Unified runtime-threshold mask (key>qrow -> 0) makes every step identical;
// A's fully-masked last tile contributes zeros naturally.
// Q bf16 [B,H,S,D] (exp2-scaled); K [B,H,S,D]; V [B,H,D,S]. Out bf16 [B,S,H,D].
// ---------------------------------------------------------------------------
__global__ __launch_bounds__(256, 1) void attn_kernel(
    const short* __restrict__ Q, const short* __restrict__ K, const short* __restrict__ V,
    short* __restrict__ AO)
{
    const int bh = blockIdx.x;
    const int qb = (gridDim.y - 1 - blockIdx.y) * 128;
    const int t = threadIdx.x;
    const int wave = t >> 6, lane = t & 63;
    const int quad = lane >> 4, l15 = lane & 15;

    const short* Qp = Q + (size_t)bh * (S_*D_);
    const short* Kp = K + (size_t)bh * (S_*D_);
    const short* Vp = V + (size_t)bh * (S_*D_);

    // per wave: [parity 0/1][qtile A/B] x (16 x 72)
    __shared__ __align__(16) short Psl[4*4*16*72];
    short* const pwav = Psl + wave*(4*16*72);
    short* const P0A = pwav;
    short* const P0B = pwav + 16*72;
    short* const P1A = pwav + 2*16*72;
    short* const P1B = pwav + 3*16*72;

    const int qA = qb + wave*16;
    const int qB = qb + 64 + wave*16;
    const short* qa = Qp + (size_t)(qA + l15)*D_ + quad*8;
    const short8v qA0 = *(const short8v*)qa, qA1 = *(const short8v*)(qa + 32);
    const short* qbp = Qp + (size_t)(qB + l15)*D_ + quad*8;
    const short8v qB0 = *(const short8v*)qbp, qB1 = *(const short8v*)(qbp + 32);

    // global row of r=0 for this lane's quad, per q-tile
    const int qrbA = qA + quad*4;
    const int qrbB = qB + quad*4;

    floatx4 oA[4], oB[4];
    #pragma unroll
    for (int i=0;i<4;i++) { oA[i] = (floatx4){0,0,0,0}; oB[i] = (floatx4){0,0,0,0}; }
    float tsA[4] = {0,0,0,0}, tsB[4] = {0,0,0,0};

    const int L = (qb >> 6) + 2;     // ntiles; even

    auto load_k = [&](short8v (&kb)[4][2], int kt) {
        const int k0 = kt << 6;
        #pragma unroll
        for (int h=0; h<4; h++) {
            const short* kr = Kp + (size_t)(k0 + 4*l15 + h)*D_ + quad*8;
            kb[h][0] = *(const short8v*)kr;
            kb[h][1] = *(const short8v*)(kr + 32);
        }
    };
    auto load_v = [&](short8v (&vb)[4][2], int kt) {
        const int k0 = kt << 6;
        #pragma unroll
        for (int dt=0; dt<4; dt++) {
            const short* vr = Vp + (size_t)(dt*16 + l15)*S_ + k0 + quad*8;
            vb[dt][0] = *(const short8v*)vr;
            vb[dt][1] = *(const short8v*)(vr + 32);
        }
    };
    auto qk = [&](short8v (&kb)[4][2], const short8v& q0f, const short8v& q1f,
                  floatx4 (&s)[4]) {
        #pragma unroll
        for (int h=0; h<4; h++) {
            s[h] = (floatx4){0.f,0.f,0.f,0.f};
            s[h] = __builtin_amdgcn_mfma_f32_16x16x32_bf16(q0f, kb[h][0], s[h], 0,0,0);
            s[h] = __builtin_amdgcn_mfma_f32_16x16x32_bf16(q1f, kb[h][1], s[h], 0,0,0);
        }
    };
    // unified softmax: key k0+4*l15+h contributes 0 if > qrow (causal)
    auto soft_u = [&](floatx4 (&s)[4], float* ts, short* pw, int qrb, int k0) {
        const int kk = k0 + 4*l15;
        #pragma unroll
        for (int r=0; r<4; r++) {
            const int qr = qrb + r;
            float p[4];
            #pragma unroll
            for (int h=0; h<4; h++) {
                const float e = fast_exp2(s[h][r]);
                p[h] = (kk + h > qr) ? 0.f : e;
            }
            ts[r] += (p[0] + p[1]) + (p[2] + p[3]);
            int2 pkv = { (int)pk_bf16(p[0], p[1]), (int)pk_bf16(p[2], p[3]) };
            *(int2*)(pw + (quad*4 + r)*72 + l15*4) = pkv;
        }
    };
    auto pv = [&](short8v (&vb)[4][2], const short* pw, floatx4 (&o)[4]) {
        const short8v pf0 = *(const short8v*)(pw + l15*72 + quad*8);
        const short8v pf1 = *(const short8v*)(pw + l15*72 + 32 + quad*8);
        #pragma unroll
        for (int dt=0; dt<4; dt++) {
            o[dt] = __builtin_amdgcn_mfma_f32_16x16x32_bf16(pf0, vb[dt][0], o[dt], 0,0,0);
            o[dt] = __builtin_amdgcn_mfma_f32_16x16x32_bf16(pf1, vb[dt][1], o[dt], 0,0,0);
        }
    };

    short8v kX[4][2], kY[4][2], vX[4][2], vY[4][2];

    // ---- prologue: tile 0 (even: kX/vX -> P0) ----
    load_k(kX, 0);
    load_v(vX, 0);
    {
        floatx4 sA[4], sB[4];
        qk(kX, qA0, qA1, sA);
        qk(kX, qB0, qB1, sB);
        load_k(kY, 1);
        soft_u(sA, tsA, P0A, qrbA, 0);
        soft_u(sB, tsB, P0B, qrbB, 0);
        load_v(vY, 1);
    }

    // ---- main loop: tiles 1..L-1, 2x unrolled, static parity ----
    int kt = 1;
    for (;;) {
        // odd tile kt: kY/vY -> P1; pv consumes even tile kt-1 (vX, P0)
        {
            floatx4 sA[4], sB[4];
            qk(kY, qA0, qA1, sA);
            qk(kY, qB0, qB1, sB);
            if (kt + 1 < L) load_k(kX, kt + 1);
            pv(vX, P0A, oA);
            pv(vX, P0B, oB);
            const int k0 = kt << 6;
            soft_u(sA, tsA, P1A, qrbA, k0);
            soft_u(sB, tsB, P1B, qrbB, k0);
            if (kt + 1 < L) load_v(vX, kt + 1);
        }
        kt++;
        if (kt >= L) break;
        // even tile kt: kX/vX -> P0; pv consumes odd tile kt-1 (vY, P1)
        {
            floatx4 sA[4], sB[4];
            qk(kX, qA0, qA1, sA);
            qk(kX, qB0, qB1, sB);
            if (kt + 1 < L) load_k(kY, kt + 1);
            pv(vY, P1A, oA);
            pv(vY, P1B, oB);
            const int k0 = kt << 6;
            soft_u(sA, tsA, P0A, qrbA, k0);
            soft_u(sB, tsB, P0B, qrbB, k0);
            if (kt + 1 < L) load_v(vY, kt + 1);
        }
        kt++;
    }

    // ---- drain: last tile L-1 is always odd parity (L even) ----
    pv(vY, P1A, oA);
    pv(vY, P1B, oB);

    float lA[4], lB[4];
    #pragma unroll
    for (int r=0; r<4; r++) {
        float a = tsA[r], b = tsB[r];
        #pragma unroll
        for (int off=1; off<16; off<<=1) {
            a += __shfl_xor(a, off);
            b += __shfl_xor(b, off);
        }
        lA[r] = a; lB[r] = b;
    }

    const int b = bh >> 4, h = bh & 15;
    #pragma unroll
    for (int dt=0; dt<4; dt++) {
        #pragma unroll
        for (int r=0; r<4; r++) {
            const int d = dt*16 + l15;
            const int sA_ = qA + quad*4 + r;
            const int sB_ = qB + quad*4 + r;
            AO[((size_t)(b*S_ + sA_)*H_ + h)*D_ + d] = f2bf(oA[dt][r] / lA[r]);
            AO[((size_t)(b*S_ + sB_)*H_ + h)*D_ + d] = f2bf(oB[dt][r] / lB[r]);
        }
    }
}

// ---------------------------------------------------------------------------
// Output GEMM, m97 structure. A = AO bf16 [4096,1024]; B = Wto bf16 [n][k].
// ---------------------------------------------------------------------------
__global__ __launch_bounds__(256) void out_gemm(
    const short* __restrict__ A, const short* __restrict__ Wto,
    const float* __restrict__ bo, float* __restrict__ out)
{
    __shared__ __align__(16) short As[128*32];
    __shared__ __align__(16) short Bs[128*32];

    const int t = threadIdx.x;
    const int wave = t >> 6, lane = t & 63;
    const int quad = lane >> 4, l15 = lane & 15;
    const int m0 = blockIdx.y*128, n0 = blockIdx.x*128;
    const int mq = (wave & 1)*64, nq = (wave >> 1)*64;
    const int srow = lane >> 2, scol = (lane & 3)*8;

    floatx4 acc[4][4];
    #pragma unroll
    for (int i=0;i<4;i++)
        #pragma unroll
        for (int j=0;j<4;j++) acc[i][j] = (floatx4){0.f,0.f,0.f,0.f};

    for (int k0 = 0; k0 < E_; k0 += 32) {
        #pragma unroll
        for (int p=0;p<2;p++) {
            const int rb = 16*(wave*2 + p);
            gl2lds16(A   + (size_t)(m0+rb+srow)*E_ + k0 + scol, &As[rb*32]);
            gl2lds16(Wto + (size_t)(n0+rb+srow)*E_ + k0 + scol, &Bs[rb*32]);
        }
        __syncthreads();
        short8v a[4], b[4];
        #pragma unroll
        for (int mt=0;mt<4;mt++) a[mt] = *(const short8v*)&As[(mq+mt*16+l15)*32 + quad*8];
        #pragma unroll
        for (int nt=0;nt<4;nt++) b[nt] = *(const short8v*)&Bs[(nq+nt*16+l15)*32 + quad*8];
        #pragma unroll
        for (int mt=0;mt<4;mt++)
            #pragma unroll
            for (int nt=0;nt<4;nt++)
                acc[mt][nt] = __builtin_amdgcn_mfma_f32_16x16x32_bf16(a[mt], b[nt], acc[mt][nt], 0,0,0);
        __syncthreads();
    }

    #pragma unroll
    for (int nt=0;nt<4;nt++) {
        const int n = n0 + nq + nt*16 + l15;
        const float bias = bo[n];
        #pragma unroll
        for (int mt=0;mt<4;mt++) {
            #pragma unroll
            for (int r=0;r<4;r++) {
                const int m = m0 + mq + mt*16 + quad*4 + r;
                out[(size_t)m*E_ + n] = acc[mt][nt][r] + bias;
            }
        }
    }
}

extern "C" void kernel_launch(void* const* d_in, const int* in_sizes, int n_in,
                              void* d_out, int out_size, void* d_ws, size_t ws_size,
                              hipStream_t stream)
{
    const float* x  = (const float*)d_in[0];
    const float* Wq = (const float*)d_in[1];
    const float* bq = (const float*)d_in[2];
    const float* Wk = (const float*)d_in[3];
    const float* bk = (const float*)d_in[4];
    const float* Wv = (const float*)d_in[5];
    const float* bv = (const float*)d_in[6];
    const float* Wo = (const float*)d_in[7];
    const float* bo = (const float*)d_in[8];

    short* xb  = (short*)d_ws;                   // bf16 [4096,1024]
    short* Tq  = xb  + (size_t)M_ * E_;          // bf16 Wq^T [n][k]
    short* Tk  = Tq  + (size_t)E_ * E_;
    short* Tv  = Tk  + (size_t)E_ * E_;
    short* To  = Tv  + (size_t)E_ * E_;
    short* Qw  = To  + (size_t)E_ * E_;          // bf16 [B,H,S,D] (exp2-scaled)
    short* Kw  = Qw  + (size_t)M_ * E_;          // bf16 [B,H,S,D]
    short* Vw  = Kw  + (size_t)M_ * E_;          // bf16 [B,H,D,S]
    short* AOw = Vw  + (size_t)M_ * E_;          // bf16 [B,S,H,D]

    dim3 blk(256);
    convert_x<<<dim3((M_*E_)/(256*8)), blk, 0, stream>>>(x, xb);
    transpose_w<<<dim3(E_/32, E_/32, 4), blk, 0, stream>>>(Wq, Wk, Wv, Wo, Tq, Tk, Tv, To);
    qkv_gemm<<<dim3(E_/128, M_/128, 3), blk, 0, stream>>>(xb, Tq, Tk, Tv, bq, bk, bv, Qw, Kw, Vw);
    attn_kernel<<<dim3(B_*H_, S_/128), blk, 0, stream>>>(Qw, Kw, Vw, AOw);
    out_gemm<<<dim3(E_/128, M_/128), blk, 0, stream>>>(AOw, To, bo, (float*)d_out);
}

// Round 8
// 206.146 us; speedup vs baseline: 1.8521x; 1.0591x over previous
//
#include <hip/hip_runtime.h>
#include <hip/hip_bf16.h>
#include <math.h>

#define B_ 2
#define S_ 2048
#define E_ 1024
#define H_ 16
#define D_ 64
#define M_ (B_*S_)

typedef __attribute__((ext_vector_type(8))) short short8v;
typedef __attribute__((ext_vector_type(4))) float floatx4;

__device__ __forceinline__ short f2bf(float f) {
    union { float f; unsigned u; } x; x.f = f;
    unsigned r = (x.u + 0x7fffu + ((x.u >> 16) & 1u)) >> 16;  // RNE
    return (short)r;
}

// pack two fp32 -> two bf16 in one v_perm_b32 (round-half-up)
__device__ __forceinline__ unsigned pk_bf16(float a, float b) {
    union { float f; unsigned u; } x, y;
    x.f = a; y.f = b;
    return __builtin_amdgcn_perm(y.u + 0x8000u, x.u + 0x8000u, 0x07060302u);
}

__device__ __forceinline__ float fast_exp2(float x) {
#if __has_builtin(__builtin_amdgcn_exp2f)
    return __builtin_amdgcn_exp2f(x);
#else
    return __expf(x * 0.6931471805599453f);
#endif
}

// async global->LDS, 16B per lane; LDS dest = wave-uniform base + lane*16
__device__ __forceinline__ void gl2lds16(const void* g, void* l) {
    __builtin_amdgcn_global_load_lds(
        (const __attribute__((address_space(1))) void*)g,
        (__attribute__((address_space(3))) void*)l, 16, 0, 0);
}

// ---------------------------------------------------------------------------
// Pre-pass 1: x fp32 -> bf16 flat copy.
// ---------------------------------------------------------------------------
__global__ __launch_bounds__(256) void convert_x(
    const float* __restrict__ x, short* __restrict__ xb)
{
    const size_t i = ((size_t)blockIdx.x*256 + threadIdx.x) * 8;
    float4 a = *(const float4*)(x + i);
    float4 b = *(const float4*)(x + i + 4);
    int4 p = { (int)pk_bf16(a.x,a.y), (int)pk_bf16(a.z,a.w),
               (int)pk_bf16(b.x,b.y), (int)pk_bf16(b.z,b.w) };
    *(int4*)(xb + i) = p;
}

// ---------------------------------------------------------------------------
// Pre-pass 2: W [k][n] fp32 -> Wt [n][k] bf16 (32x32 LDS tile transpose).
// ---------------------------------------------------------------------------
__global__ __launch_bounds__(256) void transpose_w(
    const float* __restrict__ W0, const float* __restrict__ W1,
    const float* __restrict__ W2, const float* __restrict__ W3,
    short* __restrict__ T0, short* __restrict__ T1,
    short* __restrict__ T2, short* __restrict__ T3)
{
    const int z = blockIdx.z;
    const float* W = (z==0)?W0:(z==1)?W1:(z==2)?W2:W3;
    short*       T = (z==0)?T0:(z==1)?T1:(z==2)?T2:T3;
    __shared__ float tile[32][33];
    const int k0 = blockIdx.y*32, n0 = blockIdx.x*32;
    const int r = threadIdx.x >> 5, c = threadIdx.x & 31;
    #pragma unroll
    for (int i=0;i<4;i++)
        tile[r+8*i][c] = W[(size_t)(k0+r+8*i)*E_ + n0 + c];
    __syncthreads();
    #pragma unroll
    for (int i=0;i<4;i++)
        T[(size_t)(n0+r+8*i)*E_ + k0 + c] = f2bf(tile[c][r+8*i]);
}

// ---------------------------------------------------------------------------
// QKV GEMM, m97 structure: 128x128 tile, BK=32, global_load_lds staging.
// Q out: bf16 [B,H,S,D], exp2-scaled.
// K out: per-(bh, 64-key tile) contiguous 8KB, chunk-swizzled:
//   chunk c = kk*8 + (dq ^ ((kk>>2)&7)), elem = d&7   (kk=key&63, dq=d>>3)
// V out: per-(bh, tile) contiguous 8KB [d][key], chunk-swizzled:
//   chunk c = d*8 + (kq ^ (d&7)),        elem = key&7  (kq=(key&63)>>3)
// Swizzles make attn's post-DMA LDS fragment reads bank-uniform.
// ---------------------------------------------------------------------------
__global__ __launch_bounds__(256) void qkv_gemm(
    const short* __restrict__ xb,
    const short* __restrict__ Wtq, const short* __restrict__ Wtk, const short* __restrict__ Wtv,
    const float* __restrict__ bq, const float* __restrict__ bk, const float* __restrict__ bv,
    short* __restrict__ Qo, short* __restrict__ Ko, short* __restrict__ Vo)
{
    const int z = blockIdx.z;
    const short* Wt = (z==0) ? Wtq : (z==1) ? Wtk : Wtv;
    const float* bb = (z==0) ? bq  : (z==1) ? bk  : bv;
    short* out      = (z==0) ? Qo  : (z==1) ? Ko  : Vo;
    const float sc  = (z==0) ? 0.18033688011112042f : 1.0f;

    __shared__ __align__(16) short As[128*32];
    __shared__ __align__(16) short Bs[128*32];

    const int t = threadIdx.x;
    const int wave = t >> 6, lane = t & 63;
    const int quad = lane >> 4, l15 = lane & 15;
    const int m0 = blockIdx.y*128, n0 = blockIdx.x*128;
    const int mq = (wave & 1)*64, nq = (wave >> 1)*64;
    const int srow = lane >> 2, scol = (lane & 3)*8;

    floatx4 acc[4][4];
    #pragma unroll
    for (int i=0;i<4;i++)
        #pragma unroll
        for (int j=0;j<4;j++) acc[i][j] = (floatx4){0.f,0.f,0.f,0.f};

    for (int k0 = 0; k0 < E_; k0 += 32) {
        #pragma unroll
        for (int p=0;p<2;p++) {
            const int rb = 16*(wave*2 + p);
            gl2lds16(xb + (size_t)(m0+rb+srow)*E_ + k0 + scol, &As[rb*32]);
            gl2lds16(Wt + (size_t)(n0+rb+srow)*E_ + k0 + scol, &Bs[rb*32]);
        }
        __syncthreads();
        short8v a[4], b[4];
        #pragma unroll
        for (int mt=0;mt<4;mt++) a[mt] = *(const short8v*)&As[(mq+mt*16+l15)*32 + quad*8];
        #pragma unroll
        for (int nt=0;nt<4;nt++) b[nt] = *(const short8v*)&Bs[(nq+nt*16+l15)*32 + quad*8];
        #pragma unroll
        for (int mt=0;mt<4;mt++)
            #pragma unroll
            for (int nt=0;nt<4;nt++)
                acc[mt][nt] = __builtin_amdgcn_mfma_f32_16x16x32_bf16(a[mt], b[nt], acc[mt][nt], 0,0,0);
        __syncthreads();
    }

    #pragma unroll
    for (int nt=0;nt<4;nt++) {
        const int n = n0 + nq + nt*16 + l15;
        const float bias = bb[n];
        const int h = n >> 6, d = n & 63;
        #pragma unroll
        for (int mt=0;mt<4;mt++) {
            #pragma unroll
            for (int r=0;r<4;r++) {
                const int m = m0 + mq + mt*16 + quad*4 + r;
                const int b2 = m >> 11, s = m & (S_-1);
                const int bh = (b2<<4) + h;
                const float v = (acc[mt][nt][r] + bias) * sc;
                if (z == 0) {
                    out[((size_t)bh*S_ + s)*D_ + d] = f2bf(v);
                } else if (z == 1) {
                    const int ts = s >> 6, kk = s & 63;
                    const int c = kk*8 + ((d>>3) ^ ((kk>>2)&7));
                    out[((size_t)bh*32 + ts)*4096 + c*8 + (d&7)] = f2bf(v);
                } else {
                    const int ts = s >> 6, sk = s & 63;
                    const int c = d*8 + ((sk>>3) ^ (d&7));
                    out[((size_t)bh*32 + ts)*4096 + c*8 + (sk&7)] = f2bf(v);
                }
            }
        }
    }
}

// ---------------------------------------------------------------------------
// Causal flash attention, LDS-staged K/V (R8):
// R7 was L2-BW-bound: each of 4 waves redundantly loaded the 16KB K+V tile
// (128 KB/CU/tile ~ 2300 cyc). Now one global_load_lds stage per block
// (L2 /4), waves read fragments from LDS (swizzled layouts -> bank-uniform).
// Per iter t (p=t&1): barrier; stage(t+1 -> buf 1-p); Kfrags(buf p); qk(t);
// pv(t-1) [P parity + V regs]; Vfrags(buf p)->regs; soft(t)->P[p].
// 2 q-tiles/wave, 64-key tiles, no-max exp2 softmax, unified causal mask.
// Q bf16 [B,H,S,D] exp2-scaled; K/V tiled-swizzled (see qkv_gemm).
// Out bf16 [B,S,H,D].
// ---------------------------------------------------------------------------
__global__ __launch_bounds__(256, 1) void attn_kernel(
    const short* __restrict__ Q, const short* __restrict__ K, const short* __restrict__ V,
    short* __restrict__ AO)
{
    const int bh = blockIdx.x;
    const int qb = (gridDim.y - 1 - blockIdx.y) * 128;
    const int t = threadIdx.x;
    const int wave = t >> 6, lane = t & 63;
    const int quad = lane >> 4, l15 = lane & 15;

    const short* Qp = Q + (size_t)bh * (S_*D_);
    const short* Kp = K + (size_t)bh * (S_*D_);   // 32 tiles * 4096 shorts
    const short* Vp = V + (size_t)bh * (S_*D_);

    __shared__ __align__(16) short KVs[2][8192];          // [parity][K 8KB | V 8KB]
    __shared__ __align__(16) short Psl[2][4][2][16*72];   // [parity][wave][qtile]

    const int qA = qb + wave*16;
    const int qB = qb + 64 + wave*16;
    const short* qa = Qp + (size_t)(qA + l15)*D_ + quad*8;
    const short8v qA0 = *(const short8v*)qa, qA1 = *(const short8v*)(qa + 32);
    const short* qbp = Qp + (size_t)(qB + l15)*D_ + quad*8;
    const short8v qB0 = *(const short8v*)qbp, qB1 = *(const short8v*)(qbp + 32);

    const int qrbA = qA + quad*4;
    const int qrbB = qB + quad*4;

    floatx4 oA[4], oB[4];
    #pragma unroll
    for (int i=0;i<4;i++) { oA[i] = (floatx4){0,0,0,0}; oB[i] = (floatx4){0,0,0,0}; }
    float tsA[4] = {0,0,0,0}, tsB[4] = {0,0,0,0};

    const int L = (qb >> 6) + 2;     // #tiles; even

    const int swz = l15 & 7;         // chunk-residue swizzle key

    // stage tile kt into KVs[p]: wave 0/1 -> K halves, wave 2/3 -> V halves
    auto stage = [&](int kt, int p) {
        const short* src = ((wave < 2) ? Kp : Vp) + (size_t)kt*4096 + (wave&1)*2048 + lane*8;
        short* dst = &KVs[p][((wave < 2) ? 0 : 4096) + (wave&1)*2048];
        #pragma unroll
        for (int c=0;c<4;c++)
            gl2lds16(src + c*512, dst + c*512);
    };
    // QK for both q-tiles; K B-frag chunk c = (4*l15+h)*8 + (dq ^ swz)
    auto qk2 = [&](const short* KL, floatx4 (&sA)[4], floatx4 (&sB)[4]) {
        #pragma unroll
        for (int h=0; h<4; h++) {
            const int rowc = (4*l15 + h)*8;
            short8v b0 = *(const short8v*)(KL + (rowc + (quad       ^ swz))*8);
            short8v b1 = *(const short8v*)(KL + (rowc + ((4 + quad) ^ swz))*8);
            sA[h] = (floatx4){0.f,0.f,0.f,0.f};
            sA[h] = __builtin_amdgcn_mfma_f32_16x16x32_bf16(qA0, b0, sA[h], 0,0,0);
            sA[h] = __builtin_amdgcn_mfma_f32_16x16x32_bf16(qA1, b1, sA[h], 0,0,0);
            sB[h] = (floatx4){0.f,0.f,0.f,0.f};
            sB[h] = __builtin_amdgcn_mfma_f32_16x16x32_bf16(qB0, b0, sB[h], 0,0,0);
            sB[h] = __builtin_amdgcn_mfma_f32_16x16x32_bf16(qB1, b1, sB[h], 0,0,0);
        }
    };
    // unified causal softmax; key = k0 + 4*l15 + h
    auto soft_u = [&](floatx4 (&s)[4], float* ts, short* pw, int qrb, int k0) {
        const int kk = k0 + 4*l15;
        #pragma unroll
        for (int r=0; r<4; r++) {
            const int qr = qrb + r;
            float p[4];
            #pragma unroll
            for (int h=0; h<4; h++) {
                const float e = fast_exp2(s[h][r]);
                p[h] = (kk + h > qr) ? 0.f : e;
            }
            ts[r] += (p[0] + p[1]) + (p[2] + p[3]);
            int2 pkv = { (int)pk_bf16(p[0], p[1]), (int)pk_bf16(p[2], p[3]) };
            *(int2*)(pw + (quad*4 + r)*72 + l15*4) = pkv;
        }
    };
    // V frags from LDS into regs; chunk c = (dt*16+l15)*8 + (kq ^ swz)
    short8v vr[4][2];
    auto loadv = [&](const short* VL) {
        #pragma unroll
        for (int dt=0; dt<4; dt++) {
            const int rowc = (dt*16 + l15)*8;
            vr[dt][0] = *(const short8v*)(VL + (rowc + (quad       ^ swz))*8);
            vr[dt][1] = *(const short8v*)(VL + (rowc + ((4 + quad) ^ swz))*8);
        }
    };
    auto pv = [&](const short* pw, floatx4 (&o)[4]) {
        const short8v pf0 = *(const short8v*)(pw + l15*72 + quad*8);
        const short8v pf1 = *(const short8v*)(pw + l15*72 + 32 + quad*8);
        #pragma unroll
        for (int dt=0; dt<4; dt++) {
            o[dt] = __builtin_amdgcn_mfma_f32_16x16x32_bf16(pf0, vr[dt][0], o[dt], 0,0,0);
            o[dt] = __builtin_amdgcn_mfma_f32_16x16x32_bf16(pf1, vr[dt][1], o[dt], 0,0,0);
        }
    };

    // ---- prologue: tile 0 ----
    stage(0, 0);
    __syncthreads();                     // drain stage(0)
    stage(1, 1);                         // L >= 2 always
    {
        const short* KL = &KVs[0][0];
        floatx4 sA[4], sB[4];
        qk2(KL, sA, sB);
        loadv(&KVs[0][4096]);
        soft_u(sA, tsA, &Psl[0][wave][0][0], qrbA, 0);
        soft_u(sB, tsB, &Psl[0][wave][1][0], qrbB, 0);
    }

    // ---- main loop: tiles 1..L-1 ----
    for (int kt = 1; kt < L; kt++) {
        const int p = kt & 1;
        __syncthreads();                 // stage(kt) done; all waves off buf 1-p
        if (kt + 1 < L) stage(kt + 1, p ^ 1);
        const short* KL = &KVs[p][0];
        floatx4 sA[4], sB[4];
        qk2(KL, sA, sB);
        // PV for tile kt-1: P parity 1-p, V in regs
        pv(&Psl[p^1][wave][0][0], oA);
        pv(&Psl[p^1][wave][1][0], oB);
        loadv(&KVs[p][4096]);            // V(kt) -> regs (after pv consumed V(kt-1))
        const int k0 = kt << 6;
        soft_u(sA, tsA, &Psl[p][wave][0][0], qrbA, k0);
        soft_u(sB, tsB, &Psl[p][wave][1][0], qrbB, k0);
    }

    // ---- drain: PV for tile L-1 (parity (L-1)&1 = 1, L even) ----
    pv(&Psl[1][wave][0][0], oA);
    pv(&Psl[1][wave][1][0], oB);

    float lA[4], lB[4];
    #pragma unroll
    for (int r=0; r<4; r++) {
        float a = tsA[r], b = tsB[r];
        #pragma unroll
        for (int off=1; off<16; off<<=1) {
            a += __shfl_xor(a, off);
            b += __shfl_xor(b, off);
        }
        lA[r] = a; lB[r] = b;
    }

    const int b = bh >> 4, h = bh & 15;
    #pragma unroll
    for (int dt=0; dt<4; dt++) {
        #pragma unroll
        for (int r=0; r<4; r++) {
            const int d = dt*16 + l15;
            const int sA_ = qA + quad*4 + r;
            const int sB_ = qB + quad*4 + r;
            AO[((size_t)(b*S_ + sA_)*H_ + h)*D_ + d] = f2bf(oA[dt][r] / lA[r]);
            AO[((size_t)(b*S_ + sB_)*H_ + h)*D_ + d] = f2bf(oB[dt][r] / lB[r]);
        }
    }
}

// ---------------------------------------------------------------------------
// Output GEMM, m97 structure. A = AO bf16 [4096,1024]; B = Wto bf16 [n][k].
// ---------------------------------------------------------------------------
__global__ __launch_bounds__(256) void out_gemm(
    const short* __restrict__ A, const short* __restrict__ Wto,
    const float* __restrict__ bo, float* __restrict__ out)
{
    __shared__ __align__(16) short As[128*32];
    __shared__ __align__(16) short Bs[128*32];

    const int t = threadIdx.x;
    const int wave = t >> 6, lane = t & 63;
    const int quad = lane >> 4, l15 = lane & 15;
    const int m0 = blockIdx.y*128, n0 = blockIdx.x*128;
    const int mq = (wave & 1)*64, nq = (wave >> 1)*64;
    const int srow = lane >> 2, scol = (lane & 3)*8;

    floatx4 acc[4][4];
    #pragma unroll
    for (int i=0;i<4;i++)
        #pragma unroll
        for (int j=0;j<4;j++) acc[i][j] = (floatx4){0.f,0.f,0.f,0.f};

    for (int k0 = 0; k0 < E_; k0 += 32) {
        #pragma unroll
        for (int p=0;p<2;p++) {
            const int rb = 16*(wave*2 + p);
            gl2lds16(A   + (size_t)(m0+rb+srow)*E_ + k0 + scol, &As[rb*32]);
            gl2lds16(Wto + (size_t)(n0+rb+srow)*E_ + k0 + scol, &Bs[rb*32]);
        }
        __syncthreads();
        short8v a[4], b[4];
        #pragma unroll
        for (int mt=0;mt<4;mt++) a[mt] = *(const short8v*)&As[(mq+mt*16+l15)*32 + quad*8];
        #pragma unroll
        for (int nt=0;nt<4;nt++) b[nt] = *(const short8v*)&Bs[(nq+nt*16+l15)*32 + quad*8];
        #pragma unroll
        for (int mt=0;mt<4;mt++)
            #pragma unroll
            for (int nt=0;nt<4;nt++)
                acc[mt][nt] = __builtin_amdgcn_mfma_f32_16x16x32_bf16(a[mt], b[nt], acc[mt][nt], 0,0,0);
        __syncthreads();
    }

    #pragma unroll
    for (int nt=0;nt<4;nt++) {
        const int n = n0 + nq + nt*16 + l15;
        const float bias = bo[n];
        #pragma unroll
        for (int mt=0;mt<4;mt++) {
            #pragma unroll
            for (int r=0;r<4;r++) {
                const int m = m0 + mq + mt*16 + quad*4 + r;
                out[(size_t)m*E_ + n] = acc[mt][nt][r] + bias;
            }
        }
    }
}

extern "C" void kernel_launch(void* const* d_in, const int* in_sizes, int n_in,
                              void* d_out, int out_size, void* d_ws, size_t ws_size,
                              hipStream_t stream)
{
    const float* x  = (const float*)d_in[0];
    const float* Wq = (const float*)d_in[1];
    const float* bq = (const float*)d_in[2];
    const float* Wk = (const float*)d_in[3];
    const float* bk = (const float*)d_in[4];
    const float* Wv = (const float*)d_in[5];
    const float* bv = (const float*)d_in[6];
    const float* Wo = (const float*)d_in[7];
    const float* bo = (const float*)d_in[8];

    short* xb  = (short*)d_ws;                   // bf16 [4096,1024]
    short* Tq  = xb  + (size_t)M_ * E_;          // bf16 Wq^T [n][k]
    short* Tk  = Tq  + (size_t)E_ * E_;
    short* Tv  = Tk  + (size_t)E_ * E_;
    short* To  = Tv  + (size_t)E_ * E_;
    short* Qw  = To  + (size_t)E_ * E_;          // bf16 [B,H,S,D] (exp2-scaled)
    short* Kw  = Qw  + (size_t)M_ * E_;          // bf16 tiled-swizzled K
    short* Vw  = Kw  + (size_t)M_ * E_;          // bf16 tiled-swizzled V
    short* AOw = Vw  + (size_t)M_ * E_;          // bf16 [B,S,H,D]

    dim3 blk(256);
    convert_x<<<dim3((M_*E_)/(256*8)), blk, 0, stream>>>(x, xb);
    transpose_w<<<dim3(E_/32, E_/32, 4), blk, 0, stream>>>(Wq, Wk, Wv, Wo, Tq, Tk, Tv, To);
    qkv_gemm<<<dim3(E_/128, M_/128, 3), blk, 0, stream>>>(xb, Tq, Tk, Tv, bq, bk, bv, Qw, Kw, Vw);
    attn_kernel<<<dim3(B_*H_, S_/128), blk, 0, stream>>>(Qw, Kw, Vw, AOw);
    out_gemm<<<dim3(E_/128, M_/128), blk, 0, stream>>>(AOw, To, bo, (float*)d_out);
}

// Round 9
// 196.554 us; speedup vs baseline: 1.9425x; 1.0488x over previous
//
#include <hip/hip_runtime.h>
#include <hip/hip_bf16.h>
#include <math.h>

#define B_ 2
#define S_ 2048
#define E_ 1024
#define H_ 16
#define D_ 64
#define M_ (B_*S_)

typedef __attribute__((ext_vector_type(8))) short short8v;
typedef __attribute__((ext_vector_type(4))) float floatx4;

__device__ __forceinline__ short f2bf(float f) {
    union { float f; unsigned u; } x; x.f = f;
    unsigned r = (x.u + 0x7fffu + ((x.u >> 16) & 1u)) >> 16;  // RNE
    return (short)r;
}

// pack two fp32 -> two bf16 in one v_perm_b32 (round-half-up)
__device__ __forceinline__ unsigned pk_bf16(float a, float b) {
    union { float f; unsigned u; } x, y;
    x.f = a; y.f = b;
    return __builtin_amdgcn_perm(y.u + 0x8000u, x.u + 0x8000u, 0x07060302u);
}

__device__ __forceinline__ float fast_exp2(float x) {
#if __has_builtin(__builtin_amdgcn_exp2f)
    return __builtin_amdgcn_exp2f(x);
#else
    return __expf(x * 0.6931471805599453f);
#endif
}

// async global->LDS, 16B per lane; LDS dest = wave-uniform base + lane*16
__device__ __forceinline__ void gl2lds16(const void* g, void* l) {
    __builtin_amdgcn_global_load_lds(
        (const __attribute__((address_space(1))) void*)g,
        (__attribute__((address_space(3))) void*)l, 16, 0, 0);
}

// XOR-swizzled fragment offset into a 64-col bf16 LDS tile:
// logical (row, 16B-chunk cg) lives at row*64 + ((cg ^ (row&7))*8).
// Staged by reading global chunk ((l&7)^(l>>3)) per lane (see stage8 uses).
__device__ __forceinline__ int swz_off(int row, int cg) {
    return row*64 + (((cg ^ (row & 7)) & 7) << 3);
}

// ---------------------------------------------------------------------------
// Pre-pass 1: x fp32 -> bf16 flat copy.
// ---------------------------------------------------------------------------
__global__ __launch_bounds__(256) void convert_x(
    const float* __restrict__ x, short* __restrict__ xb)
{
    const size_t i = ((size_t)blockIdx.x*256 + threadIdx.x) * 8;
    float4 a = *(const float4*)(x + i);
    float4 b = *(const float4*)(x + i + 4);
    int4 p = { (int)pk_bf16(a.x,a.y), (int)pk_bf16(a.z,a.w),
               (int)pk_bf16(b.x,b.y), (int)pk_bf16(b.z,b.w) };
    *(int4*)(xb + i) = p;
}

// ---------------------------------------------------------------------------
// Pre-pass 2: W [k][n] fp32 -> Wt [n][k] bf16 (32x32 LDS tile transpose).
// ---------------------------------------------------------------------------
__global__ __launch_bounds__(256) void transpose_w(
    const float* __restrict__ W0, const float* __restrict__ W1,
    const float* __restrict__ W2, const float* __restrict__ W3,
    short* __restrict__ T0, short* __restrict__ T1,
    short* __restrict__ T2, short* __restrict__ T3)
{
    const int z = blockIdx.z;
    const float* W = (z==0)?W0:(z==1)?W1:(z==2)?W2:W3;
    short*       T = (z==0)?T0:(z==1)?T1:(z==2)?T2:T3;
    __shared__ float tile[32][33];
    const int k0 = blockIdx.y*32, n0 = blockIdx.x*32;
    const int r = threadIdx.x >> 5, c = threadIdx.x & 31;
    #pragma unroll
    for (int i=0;i<4;i++)
        tile[r+8*i][c] = W[(size_t)(k0+r+8*i)*E_ + n0 + c];
    __syncthreads();
    #pragma unroll
    for (int i=0;i<4;i++)
        T[(size_t)(n0+r+8*i)*E_ + k0 + c] = f2bf(tile[c][r+8*i]);
}

// ---------------------------------------------------------------------------
// Fused QKV GEMM: A = xb bf16 [4096,1024]; B = Wt bf16 [3072][1024]
// (Tq|Tk|Tv contiguous). 128x128 tile, BK=64 (32 MFMA/barrier, 16 iters).
// 1-D grid 768, XCD swizzle: m = lin&31, n = lin>>5 -> each XCD sees only
// 4 A-strips (A refetch 64->8 MB). LDS XOR-chunk swizzle kills the 8-way
// b128 bank conflicts of the 128B-row layout.
// z = nf0>>10 (block-uniform): 0->Q [B,H,S,D] exp2-scaled; 1->K swizzled
// tiles; 2->V swizzled [d][key] tiles (attn-side layouts, unchanged).
// ---------------------------------------------------------------------------
__global__ __launch_bounds__(256) void qkv_gemm(
    const short* __restrict__ xb, const short* __restrict__ Wt,
    const float* __restrict__ bq, const float* __restrict__ bk, const float* __restrict__ bv,
    short* __restrict__ Qo, short* __restrict__ Ko, short* __restrict__ Vo)
{
    __shared__ __align__(16) short As[128*64];
    __shared__ __align__(16) short Bs[128*64];

    const int t = threadIdx.x;
    const int wave = t >> 6, lane = t & 63;
    const int quad = lane >> 4, l15 = lane & 15;
    const int lin = blockIdx.x;
    const int m0  = (lin & 31) * 128;
    const int nf0 = (lin >> 5) * 128;          // fused col base (0..2944)
    const int z   = nf0 >> 10;
    const float* bb = (z==0) ? bq : (z==1) ? bk : bv;
    short* out      = (z==0) ? Qo : (z==1) ? Ko : Vo;
    const float sc  = (z==0) ? 0.18033688011112042f : 1.0f;

    const int mq = (wave & 1)*64, nq = (wave >> 1)*64;
    const int sr8 = lane >> 3;                     // row within 8-row slab
    const int scs = ((lane & 7) ^ sr8) * 8;        // swizzled global chunk col

    floatx4 acc[4][4];
    #pragma unroll
    for (int i=0;i<4;i++)
        #pragma unroll
        for (int j=0;j<4;j++) acc[i][j] = (floatx4){0.f,0.f,0.f,0.f};

    for (int k0 = 0; k0 < E_; k0 += 64) {
        #pragma unroll
        for (int c=0;c<4;c++) {
            const int rb = wave*32 + c*8;
            gl2lds16(xb + (size_t)(m0 +rb+sr8)*E_ + k0 + scs, &As[rb*64]);
            gl2lds16(Wt + (size_t)(nf0+rb+sr8)*E_ + k0 + scs, &Bs[rb*64]);
        }
        __syncthreads();
        #pragma unroll
        for (int ks=0; ks<2; ks++) {
            const int cg = quad + ks*4;
            short8v a[4], b[4];
            #pragma unroll
            for (int mt=0;mt<4;mt++) a[mt] = *(const short8v*)&As[swz_off(mq+mt*16+l15, cg)];
            #pragma unroll
            for (int nt=0;nt<4;nt++) b[nt] = *(const short8v*)&Bs[swz_off(nq+nt*16+l15, cg)];
            #pragma unroll
            for (int mt=0;mt<4;mt++)
                #pragma unroll
                for (int nt=0;nt<4;nt++)
                    acc[mt][nt] = __builtin_amdgcn_mfma_f32_16x16x32_bf16(a[mt], b[nt], acc[mt][nt], 0,0,0);
        }
        __syncthreads();
    }

    #pragma unroll
    for (int nt=0;nt<4;nt++) {
        const int nw = (nf0 & 1023) + nq + nt*16 + l15;   // col within this W
        const float bias = bb[nw];
        const int h = nw >> 6, d = nw & 63;
        #pragma unroll
        for (int mt=0;mt<4;mt++) {
            #pragma unroll
            for (int r=0;r<4;r++) {
                const int m = m0 + mq + mt*16 + quad*4 + r;
                const int b2 = m >> 11, s = m & (S_-1);
                const int bh = (b2<<4) + h;
                const float v = (acc[mt][nt][r] + bias) * sc;
                if (z == 0) {
                    out[((size_t)bh*S_ + s)*D_ + d] = f2bf(v);
                } else if (z == 1) {
                    const int ts = s >> 6, kk = s & 63;
                    const int c = kk*8 + ((d>>3) ^ ((kk>>2)&7));
                    out[((size_t)bh*32 + ts)*4096 + c*8 + (d&7)] = f2bf(v);
                } else {
                    const int ts = s >> 6, sk = s & 63;
                    const int c = d*8 + ((sk>>3) ^ (d&7));
                    out[((size_t)bh*32 + ts)*4096 + c*8 + (sk&7)] = f2bf(v);
                }
            }
        }
    }
}

// ---------------------------------------------------------------------------
// Causal flash attention, LDS-staged K/V (unchanged from R8).
// ---------------------------------------------------------------------------
__global__ __launch_bounds__(256, 1) void attn_kernel(
    const short* __restrict__ Q, const short* __restrict__ K, const short* __restrict__ V,
    short* __restrict__ AO)
{
    const int bh = blockIdx.x;
    const int qb = (gridDim.y - 1 - blockIdx.y) * 128;
    const int t = threadIdx.x;
    const int wave = t >> 6, lane = t & 63;
    const int quad = lane >> 4, l15 = lane & 15;

    const short* Qp = Q + (size_t)bh * (S_*D_);
    const short* Kp = K + (size_t)bh * (S_*D_);
    const short* Vp = V + (size_t)bh * (S_*D_);

    __shared__ __align__(16) short KVs[2][8192];          // [parity][K 8KB | V 8KB]
    __shared__ __align__(16) short Psl[2][4][2][16*72];   // [parity][wave][qtile]

    const int qA = qb + wave*16;
    const int qB = qb + 64 + wave*16;
    const short* qa = Qp + (size_t)(qA + l15)*D_ + quad*8;
    const short8v qA0 = *(const short8v*)qa, qA1 = *(const short8v*)(qa + 32);
    const short* qbp = Qp + (size_t)(qB + l15)*D_ + quad*8;
    const short8v qB0 = *(const short8v*)qbp, qB1 = *(const short8v*)(qbp + 32);

    const int qrbA = qA + quad*4;
    const int qrbB = qB + quad*4;

    floatx4 oA[4], oB[4];
    #pragma unroll
    for (int i=0;i<4;i++) { oA[i] = (floatx4){0,0,0,0}; oB[i] = (floatx4){0,0,0,0}; }
    float tsA[4] = {0,0,0,0}, tsB[4] = {0,0,0,0};

    const int L = (qb >> 6) + 2;     // #tiles; even
    const int swz = l15 & 7;

    auto stage = [&](int kt, int p) {
        const short* src = ((wave < 2) ? Kp : Vp) + (size_t)kt*4096 + (wave&1)*2048 + lane*8;
        short* dst = &KVs[p][((wave < 2) ? 0 : 4096) + (wave&1)*2048];
        #pragma unroll
        for (int c=0;c<4;c++)
            gl2lds16(src + c*512, dst + c*512);
    };
    auto qk2 = [&](const short* KL, floatx4 (&sA)[4], floatx4 (&sB)[4]) {
        #pragma unroll
        for (int h=0; h<4; h++) {
            const int rowc = (4*l15 + h)*8;
            short8v b0 = *(const short8v*)(KL + (rowc + (quad       ^ swz))*8);
            short8v b1 = *(const short8v*)(KL + (rowc + ((4 + quad) ^ swz))*8);
            sA[h] = (floatx4){0.f,0.f,0.f,0.f};
            sA[h] = __builtin_amdgcn_mfma_f32_16x16x32_bf16(qA0, b0, sA[h], 0,0,0);
            sA[h] = __builtin_amdgcn_mfma_f32_16x16x32_bf16(qA1, b1, sA[h], 0,0,0);
            sB[h] = (floatx4){0.f,0.f,0.f,0.f};
            sB[h] = __builtin_amdgcn_mfma_f32_16x16x32_bf16(qB0, b0, sB[h], 0,0,0);
            sB[h] = __builtin_amdgcn_mfma_f32_16x16x32_bf16(qB1, b1, sB[h], 0,0,0);
        }
    };
    auto soft_u = [&](floatx4 (&s)[4], float* ts, short* pw, int qrb, int k0) {
        const int kk = k0 + 4*l15;
        #pragma unroll
        for (int r=0; r<4; r++) {
            const int qr = qrb + r;
            float p[4];
            #pragma unroll
            for (int h=0; h<4; h++) {
                const float e = fast_exp2(s[h][r]);
                p[h] = (kk + h > qr) ? 0.f : e;
            }
            ts[r] += (p[0] + p[1]) + (p[2] + p[3]);
            int2 pkv = { (int)pk_bf16(p[0], p[1]), (int)pk_bf16(p[2], p[3]) };
            *(int2*)(pw + (quad*4 + r)*72 + l15*4) = pkv;
        }
    };
    short8v vr[4][2];
    auto loadv = [&](const short* VL) {
        #pragma unroll
        for (int dt=0; dt<4; dt++) {
            const int rowc = (dt*16 + l15)*8;
            vr[dt][0] = *(const short8v*)(VL + (rowc + (quad       ^ swz))*8);
            vr[dt][1] = *(const short8v*)(VL + (rowc + ((4 + quad) ^ swz))*8);
        }
    };
    auto pv = [&](const short* pw, floatx4 (&o)[4]) {
        const short8v pf0 = *(const short8v*)(pw + l15*72 + quad*8);
        const short8v pf1 = *(const short8v*)(pw + l15*72 + 32 + quad*8);
        #pragma unroll
        for (int dt=0; dt<4; dt++) {
            o[dt] = __builtin_amdgcn_mfma_f32_16x16x32_bf16(pf0, vr[dt][0], o[dt], 0,0,0);
            o[dt] = __builtin_amdgcn_mfma_f32_16x16x32_bf16(pf1, vr[dt][1], o[dt], 0,0,0);
        }
    };

    // ---- prologue: tile 0 ----
    stage(0, 0);
    __syncthreads();
    stage(1, 1);
    {
        floatx4 sA[4], sB[4];
        qk2(&KVs[0][0], sA, sB);
        loadv(&KVs[0][4096]);
        soft_u(sA, tsA, &Psl[0][wave][0][0], qrbA, 0);
        soft_u(sB, tsB, &Psl[0][wave][1][0], qrbB, 0);
    }

    for (int kt = 1; kt < L; kt++) {
        const int p = kt & 1;
        __syncthreads();
        if (kt + 1 < L) stage(kt + 1, p ^ 1);
        floatx4 sA[4], sB[4];
        qk2(&KVs[p][0], sA, sB);
        pv(&Psl[p^1][wave][0][0], oA);
        pv(&Psl[p^1][wave][1][0], oB);
        loadv(&KVs[p][4096]);
        const int k0 = kt << 6;
        soft_u(sA, tsA, &Psl[p][wave][0][0], qrbA, k0);
        soft_u(sB, tsB, &Psl[p][wave][1][0], qrbB, k0);
    }

    pv(&Psl[1][wave][0][0], oA);
    pv(&Psl[1][wave][1][0], oB);

    float lA[4], lB[4];
    #pragma unroll
    for (int r=0; r<4; r++) {
        float a = tsA[r], b = tsB[r];
        #pragma unroll
        for (int off=1; off<16; off<<=1) {
            a += __shfl_xor(a, off);
            b += __shfl_xor(b, off);
        }
        lA[r] = a; lB[r] = b;
    }

    const int b = bh >> 4, h = bh & 15;
    #pragma unroll
    for (int dt=0; dt<4; dt++) {
        #pragma unroll
        for (int r=0; r<4; r++) {
            const int d = dt*16 + l15;
            const int sA_ = qA + quad*4 + r;
            const int sB_ = qB + quad*4 + r;
            AO[((size_t)(b*S_ + sA_)*H_ + h)*D_ + d] = f2bf(oA[dt][r] / lA[r]);
            AO[((size_t)(b*S_ + sB_)*H_ + h)*D_ + d] = f2bf(oB[dt][r] / lB[r]);
        }
    }
}

// ---------------------------------------------------------------------------
// Output GEMM: 128m x 64n tiles (512 blocks = 2/CU for barrier overlap),
// BK=64, XOR-swizzled LDS, XCD swizzle m = lin&31.
// Wave w: rows [32w,32w+32) x all 64 n -> acc[2][4].
// ---------------------------------------------------------------------------
__global__ __launch_bounds__(256) void out_gemm(
    const short* __restrict__ A, const short* __restrict__ Wto,
    const float* __restrict__ bo, float* __restrict__ out)
{
    __shared__ __align__(16) short As[128*64];
    __shared__ __align__(16) short Bs[64*64];

    const int t = threadIdx.x;
    const int wave = t >> 6, lane = t & 63;
    const int quad = lane >> 4, l15 = lane & 15;
    const int lin = blockIdx.x;
    const int m0 = (lin & 31) * 128;
    const int n0 = (lin >> 5) * 64;
    const int sr8 = lane >> 3;
    const int scs = ((lane & 7) ^ sr8) * 8;

    floatx4 acc[2][4];
    #pragma unroll
    for (int i=0;i<2;i++)
        #pragma unroll
        for (int j=0;j<4;j++) acc[i][j] = (floatx4){0.f,0.f,0.f,0.f};

    for (int k0 = 0; k0 < E_; k0 += 64) {
        #pragma unroll
        for (int c=0;c<4;c++) {
            const int rb = wave*32 + c*8;
            gl2lds16(A + (size_t)(m0+rb+sr8)*E_ + k0 + scs, &As[rb*64]);
        }
        #pragma unroll
        for (int c=0;c<2;c++) {
            const int rb = wave*16 + c*8;
            gl2lds16(Wto + (size_t)(n0+rb+sr8)*E_ + k0 + scs, &Bs[rb*64]);
        }
        __syncthreads();
        #pragma unroll
        for (int ks=0; ks<2; ks++) {
            const int cg = quad + ks*4;
            short8v a[2], b[4];
            #pragma unroll
            for (int mt=0;mt<2;mt++) a[mt] = *(const short8v*)&As[swz_off(wave*32+mt*16+l15, cg)];
            #pragma unroll
            for (int nt=0;nt<4;nt++) b[nt] = *(const short8v*)&Bs[swz_off(nt*16+l15, cg)];
            #pragma unroll
            for (int mt=0;mt<2;mt++)
                #pragma unroll
                for (int nt=0;nt<4;nt++)
                    acc[mt][nt] = __builtin_amdgcn_mfma_f32_16x16x32_bf16(a[mt], b[nt], acc[mt][nt], 0,0,0);
        }
        __syncthreads();
    }

    #pragma unroll
    for (int nt=0;nt<4;nt++) {
        const int n = n0 + nt*16 + l15;
        const float bias = bo[n];
        #pragma unroll
        for (int mt=0;mt<2;mt++) {
            #pragma unroll
            for (int r=0;r<4;r++) {
                const int m = m0 + wave*32 + mt*16 + quad*4 + r;
                out[(size_t)m*E_ + n] = acc[mt][nt][r] + bias;
            }
        }
    }
}

extern "C" void kernel_launch(void* const* d_in, const int* in_sizes, int n_in,
                              void* d_out, int out_size, void* d_ws, size_t ws_size,
                              hipStream_t stream)
{
    const float* x  = (const float*)d_in[0];
    const float* Wq = (const float*)d_in[1];
    const float* bq = (const float*)d_in[2];
    const float* Wk = (const float*)d_in[3];
    const float* bk = (const float*)d_in[4];
    const float* Wv = (const float*)d_in[5];
    const float* bv = (const float*)d_in[6];
    const float* Wo = (const float*)d_in[7];
    const float* bo = (const float*)d_in[8];

    short* xb  = (short*)d_ws;                   // bf16 [4096,1024]
    short* Tq  = xb  + (size_t)M_ * E_;          // bf16 Wq^T [n][k]; Tq|Tk|Tv fused
    short* Tk  = Tq  + (size_t)E_ * E_;
    short* Tv  = Tk  + (size_t)E_ * E_;
    short* To  = Tv  + (size_t)E_ * E_;
    short* Qw  = To  + (size_t)E_ * E_;          // bf16 [B,H,S,D] (exp2-scaled)
    short* Kw  = Qw  + (size_t)M_ * E_;          // bf16 tiled-swizzled K
    short* Vw  = Kw  + (size_t)M_ * E_;          // bf16 tiled-swizzled V
    short* AOw = Vw  + (size_t)M_ * E_;          // bf16 [B,S,H,D]

    dim3 blk(256);
    convert_x<<<dim3((M_*E_)/(256*8)), blk, 0, stream>>>(x, xb);
    transpose_w<<<dim3(E_/32, E_/32, 4), blk, 0, stream>>>(Wq, Wk, Wv, Wo, Tq, Tk, Tv, To);
    qkv_gemm<<<dim3(768), blk, 0, stream>>>(xb, Tq, bq, bk, bv, Qw, Kw, Vw);
    attn_kernel<<<dim3(B_*H_, S_/128), blk, 0, stream>>>(Qw, Kw, Vw, AOw);
    out_gemm<<<dim3(512), blk, 0, stream>>>(AOw, To, bo, (float*)d_out);
}